// Round 5
// baseline (123.314 us; speedup 1.0000x reference)
//
#include <hip/hip_runtime.h>
#include <math.h>

// YOLO loss, 3 scales: G in {13,26,52}, B=32, A=3, 85 ch (5+80), IMG=416.
// Inputs (setup_inputs dict order): fm0, yt0, fm1, yt1, fm2, yt2, anchors(9x2)
// Output: 5 floats: total, xy, wh, conf, prob
//
// Hard-won notes:
//  - hipcc lowers atomicAdd(float/double) on global to CAS loops (no
//    -munsafe-fp-atomics). Contended fp atomics serialize at ~40ns/success.
//    NEVER use them. Int atomics are native and cheap.
//  - 4 small dispatches cost ~25-30us of boundary overhead; this version is
//    2 dispatches with an in-kernel soft grid barrier (512 blocks = 2/CU,
//    co-residency guaranteed by __launch_bounds__(256,2): 8 waves/CU needed,
//    VGPR can never constrain below that).
//  - Cross-XCD visibility inside one dispatch: writer does syncthreads ->
//    __threadfence (L2 wb) -> native int atomic ticket; readers use
//    __hip_atomic_load AGENT scope (bypasses stale per-XCD L2).

constexpr int   NCLS  = 80;
constexpr int   KMAX  = 32;
constexpr float IMGF  = 416.0f;

constexpr int C0 = 32 * 3 * 169;    // 16224
constexpr int C1 = 32 * 3 * 676;    // 64896
constexpr int C2 = 32 * 3 * 2704;   // 259584
constexpr int TOTAL_CELLS = C0 + C1 + C2; // 340704

constexpr int NBLK  = 512;                    // 2 blocks/CU -> safe co-residency
constexpr int NUNIT = 96 + 1440;              // 96 pos units + 1440 conf units

// ws layout (every consumed slot rewritten every call; counters zeroed by k_init):
constexpr size_t OFF_CNT   = 0;                         // int cnt[96]
constexpr size_t OFF_DONE1 = 384;                       // int (barrier ticket)
constexpr size_t OFF_DONE2 = 448;                       // int (finish ticket)
constexpr size_t OFF_PART  = 512;                       // float4 part[512]
constexpr size_t OFF_TGT   = OFF_PART + (size_t)NBLK * 16;      // 8704: float4 tgt[96][32]
constexpr size_t OFF_TGTN  = OFF_TGT + (size_t)96 * KMAX * 16;  // 57856: int tgtn[96][32]
// end = 70144 bytes (< available ws)

__device__ __forceinline__ int aload_i(const int* p) {
    return __hip_atomic_load(p, __ATOMIC_RELAXED, __HIP_MEMORY_SCOPE_AGENT);
}
__device__ __forceinline__ float aload_f(const float* p) {
    return __hip_atomic_load(p, __ATOMIC_RELAXED, __HIP_MEMORY_SCOPE_AGENT);
}
__device__ inline float sigmoidf_(float x) { return 1.0f / (1.0f + expf(-x)); }
__device__ inline float bcef_(float l, float t) {
    return fmaxf(l, 0.0f) - l * t + log1pf(expf(-fabsf(l)));
}

__global__ __launch_bounds__(128) void k_init(int* wsi) {
    int t = threadIdx.x;
    if (t < 128) wsi[t] = 0;   // zeroes bytes [0,512): cnt[96], done1, done2
}

__global__ __launch_bounds__(256, 2) void k_mega(
        const float* __restrict__ fm0, const float* __restrict__ fm1,
        const float* __restrict__ fm2,
        const float* __restrict__ yt0, const float* __restrict__ yt1,
        const float* __restrict__ yt2,
        const float* __restrict__ anch,
        int* __restrict__ cnt, float* __restrict__ tgt, int* __restrict__ tgtn,
        int* __restrict__ done1, int* __restrict__ done2,
        float* __restrict__ part, float* __restrict__ out) {
    __shared__ float4 s_t4[KMAX];
    __shared__ float  s_minx[KMAX], s_maxx[KMAX], s_miny[KMAX], s_maxy[KMAX], s_area[KMAX];
    __shared__ int    s_tn[KMAX];
    __shared__ int    s_cn;
    __shared__ float4 s_w[4];
    __shared__ int    s_last;

    int bid = blockIdx.x;
    int tid = threadIdx.x;
    int wid = tid >> 6, lane = tid & 63;

    // ================= phase 1: collect positive targets =================
    for (int t = bid * 256 + tid; t < TOTAL_CELLS; t += NBLK * 256) {
        int s, local, G;
        const float* yt;
        if (t < C0)           { s = 0; local = t;           G = 13; yt = yt0; }
        else if (t < C0 + C1) { s = 1; local = t - C0;      G = 26; yt = yt1; }
        else                  { s = 2; local = t - C0 - C1; G = 52; yt = yt2; }
        int GG = G * G;
        int b  = local / (3 * GG);
        int n  = local - b * 3 * GG;          // b-relative flattened cell index
        int yidx = local * 85;
        float obj = yt[yidx + 4];
        if (obj > 0.5f) {
            int pos = atomicAdd(&cnt[s * 32 + b], 1);   // native int atomic
            if (pos < KMAX) {
                float4 box = make_float4(yt[yidx], yt[yidx + 1], yt[yidx + 2], yt[yidx + 3]);
                reinterpret_cast<float4*>(tgt)[(s * 32 + b) * KMAX + pos] = box;
                tgtn[(s * 32 + b) * KMAX + pos] = n;
            }
        }
    }
    // ---- soft grid barrier (all 512 blocks co-resident at 2/CU) ----
    __syncthreads();                         // drain this block's stores
    if (tid == 0) {
        __threadfence();                     // write back XCD L2 to coherence point
        atomicAdd(done1, 1);
        while (__hip_atomic_load(done1, __ATOMIC_ACQUIRE, __HIP_MEMORY_SCOPE_AGENT) < NBLK)
            __builtin_amdgcn_s_sleep(2);
    }
    __syncthreads();

    // ================= phase 2: losses =================
    float ax = 0.f, aw2 = 0.f, ap = 0.f, ac = 0.f;    // thread-local partials

    for (int unit = bid; unit < NUNIT; unit += NBLK) {
        __syncthreads();                     // LDS reuse across unit iterations
        if (unit < 96) {
            // ---- positive-cell unit: one (scale,batch) ----
            int sb = unit, s = sb >> 5, b = sb & 31;
            const float *fm, *yt;
            int G, anchoff;
            if (s == 0)      { fm = fm0; yt = yt0; G = 13; anchoff = 6; }
            else if (s == 1) { fm = fm1; yt = yt1; G = 26; anchoff = 3; }
            else             { fm = fm2; yt = yt2; G = 52; anchoff = 0; }
            int GG = G * G;
            float stridef = IMGF / (float)G;
            if (tid == 0) s_cn = min(aload_i(&cnt[sb]), KMAX);
            if (tid < KMAX) {
                const float* tp = tgt + (size_t)(sb * KMAX + tid) * 4;
                s_t4[tid] = make_float4(aload_f(tp), aload_f(tp + 1),
                                        aload_f(tp + 2), aload_f(tp + 3));
                s_tn[tid] = aload_i(&tgtn[sb * KMAX + tid]);
            }
            __syncthreads();
            if (tid == 0) {                  // sort by cell index: deterministic sums
                int cn = s_cn;
                for (int i = 1; i < cn; ++i) {
                    int key = s_tn[i]; float4 kv = s_t4[i];
                    int j = i - 1;
                    while (j >= 0 && s_tn[j] > key) {
                        s_tn[j + 1] = s_tn[j]; s_t4[j + 1] = s_t4[j]; --j;
                    }
                    s_tn[j + 1] = key; s_t4[j + 1] = kv;
                }
            }
            __syncthreads();
            int cn = s_cn;
            for (int slot = wid; slot < cn; slot += 4) {
                float4 tb = s_t4[slot];
                int n  = s_tn[slot];
                int a  = n % 3;
                int sp = n / 3;
                int jj = sp % G, ii = sp / G;
                int ybase = (b * 3 * GG + n) * 85;
                int fbase = (b * 255 + a * 85) * GG + sp;
                for (int c = lane; c < NCLS; c += 64) {      // class BCE, lane-parallel
                    float pl  = fm[fbase + (5 + c) * GG];
                    float tl  = yt[ybase + 5 + c];
                    float lab = 0.99f * tl + 1.25e-4f;       // (1-delta)*t + delta/NC
                    ap += bcef_(pl, lab);
                }
                if (lane == 0) {
                    float p0 = fm[fbase];
                    float p1 = fm[fbase + GG];
                    float p2 = fm[fbase + 2 * GG];
                    float p3 = fm[fbase + 3 * GG];
                    float bcx = (sigmoidf_(p0) + (float)jj) * stridef;
                    float bcy = (sigmoidf_(p1) + (float)ii) * stridef;
                    float predx = bcx / stridef - (float)jj;
                    float predy = bcy / stridef - (float)ii;
                    float truex = tb.x / stridef - (float)jj;
                    float truey = tb.y / stridef - (float)ii;
                    float dx = truex - predx, dy = truey - predy;
                    float bscale = 2.0f - (tb.z / IMGF) * (tb.w / IMGF);
                    float aw = anch[(anchoff + a) * 2], ah = anch[(anchoff + a) * 2 + 1];
                    float pw = expf(p2) * (aw / stridef) * stridef;
                    float ph = expf(p3) * (ah / stridef) * stridef;
                    float ptw = pw / aw, pth = ph / ah;
                    float ttw = tb.z / aw, tth = tb.w / ah;
                    ttw = (ttw == 0.0f) ? 1.0f : ttw;
                    tth = (tth == 0.0f) ? 1.0f : tth;
                    ptw = (ptw == 0.0f) ? 1.0f : ptw;
                    pth = (pth == 0.0f) ? 1.0f : pth;
                    ttw = logf(fminf(fmaxf(ttw, 1e-9f), 1e9f));
                    tth = logf(fminf(fmaxf(tth, 1e-9f), 1e9f));
                    ptw = logf(fminf(fmaxf(ptw, 1e-9f), 1e9f));
                    pth = logf(fminf(fmaxf(pth, 1e-9f), 1e9f));
                    float dw = ttw - ptw, dh = tth - pth;
                    ax  += (dx * dx + dy * dy) * bscale;
                    aw2 += (dw * dw + dh * dh) * bscale;
                }
            }
        } else {
            // ---- conf unit: 256 cells of one (scale,b,a) ----
            int cb = unit - 96;
            const float *fm;
            int G, chunks, s, anchoff;
            if (cb < 96)       { fm = fm0; G = 13; chunks = 1;  s = 0; anchoff = 6; }
            else if (cb < 384) { cb -= 96;  fm = fm1; G = 26; chunks = 3;  s = 1; anchoff = 3; }
            else               { cb -= 384; fm = fm2; G = 52; chunks = 11; s = 2; anchoff = 0; }
            int chunk = cb % chunks;
            int ba    = cb / chunks;
            int b = ba / 3, a = ba % 3;
            int GG = G * G;
            float stridef = IMGF / (float)G;
            int sb = s * 32 + b;
            if (tid == 0) s_cn = min(aload_i(&cnt[sb]), KMAX);
            if (tid < KMAX) {
                const float* tp = tgt + (size_t)(sb * KMAX + tid) * 4;
                float x = aload_f(tp), y = aload_f(tp + 1);
                float w = aload_f(tp + 2), h = aload_f(tp + 3);
                s_minx[tid] = x - w * 0.5f;
                s_maxx[tid] = x + w * 0.5f;
                s_miny[tid] = y - h * 0.5f;
                s_maxy[tid] = y + h * 0.5f;
                s_area[tid] = w * h;
                s_tn[tid]   = aload_i(&tgtn[sb * KMAX + tid]);
            }
            __syncthreads();
            int sp = chunk * 256 + tid;
            if (sp < GG) {
                int jj = sp % G, ii = sp / G;
                int n = sp * 3 + a;
                int fbase = (b * 255 + a * 85) * GG + sp;
                float p0 = fm[fbase];
                float p1 = fm[fbase + GG];
                float p2 = fm[fbase + 2 * GG];
                float p3 = fm[fbase + 3 * GG];
                float p4 = fm[fbase + 4 * GG];
                float aw = anch[(anchoff + a) * 2], ah = anch[(anchoff + a) * 2 + 1];
                float cx = (sigmoidf_(p0) + (float)jj) * stridef;
                float cy = (sigmoidf_(p1) + (float)ii) * stridef;
                float pw = expf(p2) * (aw / stridef) * stridef;
                float ph = expf(p3) * (ah / stridef) * stridef;
                float pminx = cx - pw * 0.5f, pmaxx = cx + pw * 0.5f;
                float pminy = cy - ph * 0.5f, pmaxy = cy + ph * 0.5f;
                float parea = pw * ph;
                int cn = s_cn;
                float best = 0.0f, m = 0.0f;
                for (int k = 0; k < cn; ++k) {
                    if (s_tn[k] == n) m = 1.0f;
                    float iw = fminf(pmaxx, s_maxx[k]) - fmaxf(pminx, s_minx[k]);
                    float ih = fminf(pmaxy, s_maxy[k]) - fmaxf(pminy, s_miny[k]);
                    iw = fmaxf(iw, 0.0f);
                    ih = fmaxf(ih, 0.0f);
                    float inter = iw * ih;
                    float iou = inter / ((parea + s_area[k] - inter) + 1e-10f);
                    best = fmaxf(best, iou);
                }
                float ign = (cn > 0 && best < 0.5f) ? 1.0f : 0.0f;
                float bce = bcef_(p4, m);
                float d = fabsf(m - sigmoidf_(p4));
                ac += (m * bce + 0.5f * (1.0f - m) * ign * bce) * (d * d);
            }
        }
    }

    // ---- block reduction of (ax, aw2, ap, ac) ----
    for (int off = 32; off; off >>= 1) {
        ax  += __shfl_down(ax,  off);
        aw2 += __shfl_down(aw2, off);
        ap  += __shfl_down(ap,  off);
        ac  += __shfl_down(ac,  off);
    }
    if (lane == 0) s_w[wid] = make_float4(ax, aw2, ap, ac);
    __syncthreads();
    if (tid == 0) {
        float4 r0 = s_w[0], r1 = s_w[1], r2 = s_w[2], r3 = s_w[3];
        float4 v = make_float4(r0.x + r1.x + r2.x + r3.x,
                               r0.y + r1.y + r2.y + r3.y,
                               r0.z + r1.z + r2.z + r3.z,
                               r0.w + r1.w + r2.w + r3.w);
        reinterpret_cast<float4*>(part)[bid] = v;
        __threadfence();
        int prev = atomicAdd(done2, 1);
        s_last = (prev == NBLK - 1) ? 1 : 0;
    }
    __syncthreads();

    // ---- last block: final reduce + output ----
    if (s_last) {
        double dx = 0.0, dw = 0.0, dp = 0.0, dc = 0.0;
        for (int i = tid; i < NBLK; i += 256) {
            const float* pp = part + (size_t)i * 4;
            dx += (double)aload_f(pp);
            dw += (double)aload_f(pp + 1);
            dp += (double)aload_f(pp + 2);
            dc += (double)aload_f(pp + 3);
        }
        for (int off = 32; off; off >>= 1) {
            dx += __shfl_down(dx, off);
            dw += __shfl_down(dw, off);
            dp += __shfl_down(dp, off);
            dc += __shfl_down(dc, off);
        }
        __shared__ double sd[4][4];
        if (lane == 0) { sd[wid][0] = dx; sd[wid][1] = dw; sd[wid][2] = dp; sd[wid][3] = dc; }
        __syncthreads();
        if (tid == 0) {
            double X = sd[0][0] + sd[1][0] + sd[2][0] + sd[3][0];
            double W = sd[0][1] + sd[1][1] + sd[2][1] + sd[3][1];
            double P = sd[0][2] + sd[1][2] + sd[2][2] + sd[3][2];
            double C = sd[0][3] + sd[1][3] + sd[2][3] + sd[3][3];
            double xy = 5.0 * X / 32.0;
            double wh = 5.0 * W / 32.0;
            double cf = C / 32.0;
            double pb = P / 32.0;
            out[0] = (float)(xy + wh + cf + pb);
            out[1] = (float)xy;
            out[2] = (float)wh;
            out[3] = (float)cf;
            out[4] = (float)pb;
        }
    }
}

extern "C" void kernel_launch(void* const* d_in, const int* in_sizes, int n_in,
                              void* d_out, int out_size, void* d_ws, size_t ws_size,
                              hipStream_t stream) {
    const float* fm0  = (const float*)d_in[0];
    const float* yt0  = (const float*)d_in[1];
    const float* fm1  = (const float*)d_in[2];
    const float* yt1  = (const float*)d_in[3];
    const float* fm2  = (const float*)d_in[4];
    const float* yt2  = (const float*)d_in[5];
    const float* anch = (const float*)d_in[6];
    float* out = (float*)d_out;

    char* ws = (char*)d_ws;
    int*   cnt   = (int*)(ws + OFF_CNT);
    int*   done1 = (int*)(ws + OFF_DONE1);
    int*   done2 = (int*)(ws + OFF_DONE2);
    float* part  = (float*)(ws + OFF_PART);
    float* tgt   = (float*)(ws + OFF_TGT);
    int*   tgtn  = (int*)(ws + OFF_TGTN);

    k_init<<<1, 128, 0, stream>>>((int*)ws);
    k_mega<<<NBLK, 256, 0, stream>>>(
        fm0, fm1, fm2, yt0, yt1, yt2, anch,
        cnt, tgt, tgtn, done1, done2, part, out);
}

// Round 6
// 76.754 us; speedup vs baseline: 1.6066x; 1.6066x over previous
//
#include <hip/hip_runtime.h>
#include <math.h>

// YOLO loss, 3 scales: G in {13,26,52}, B=32, A=3, 85 ch (5+80), IMG=416.
// Inputs (setup_inputs dict order): fm0, yt0, fm1, yt1, fm2, yt2, anchors(9x2)
// Output: 5 floats: total, xy, wh, conf, prob
//
// Hard-won notes:
//  - hipcc lowers atomicAdd(float/double) on global to CAS loops (no
//    -munsafe-fp-atomics). Contended fp atomics serialize ~40ns/success ->
//    NEVER use them. Int atomics are native and cheap.
//  - Intra-kernel grid barriers require co-residency caps (2 blocks/CU) that
//    starve latency-bound gather phases of TLP (R5: 123us vs R4: 41us).
//    Separate dispatches + full occupancy win for this op.
//  - Ticket finalize (plain store -> __threadfence -> int atomic -> last block
//    reads partials with AGENT-scope loads) is validated on-HW (absmax 0).
//    Cross-KERNEL ws visibility needs only plain loads (dispatch boundary).

constexpr int   NCLS  = 80;
constexpr int   KMAX  = 32;
constexpr float IMGF  = 416.0f;

constexpr int C0 = 32 * 3 * 169;    // 16224
constexpr int C1 = 32 * 3 * 676;    // 64896
constexpr int C2 = 32 * 3 * 2704;   // 259584
constexpr int TOTAL_CELLS = C0 + C1 + C2; // 340704

constexpr int NBLK_POS  = 768;                   // 4 waves/blk, 1 slot/wave = 3072 slots
constexpr int NBLK_CONF = 96 + 288 + 1056;       // 1440
constexpr int NBLK_MAIN = NBLK_POS + NBLK_CONF;  // 2208

// ws layout (counters zeroed each call by k_init; all else rewritten):
constexpr size_t OFF_CNT  = 0;                                   // int cnt[96]
constexpr size_t OFF_DONE = 384;                                 // int ticket
constexpr size_t OFF_PART = 512;                                 // float4 part[2208]
constexpr size_t OFF_TGT  = OFF_PART + (size_t)NBLK_MAIN * 16;   // 35840: float4 tgt[96][32]
constexpr size_t OFF_TGTN = OFF_TGT + (size_t)96 * KMAX * 16;    // 84992: int tgtn[96][32]
// end = 97280 bytes

__device__ __forceinline__ int aload_i(const int* p) {
    return __hip_atomic_load(p, __ATOMIC_RELAXED, __HIP_MEMORY_SCOPE_AGENT);
}
__device__ __forceinline__ float aload_f(const float* p) {
    return __hip_atomic_load(p, __ATOMIC_RELAXED, __HIP_MEMORY_SCOPE_AGENT);
}
__device__ inline float sigmoidf_(float x) { return 1.0f / (1.0f + expf(-x)); }
__device__ inline float bcef_(float l, float t) {
    return fmaxf(l, 0.0f) - l * t + log1pf(expf(-fabsf(l)));
}

__global__ __launch_bounds__(128) void k_init(int* wsi) {
    int t = threadIdx.x;
    if (t < 128) wsi[t] = 0;   // zeroes bytes [0,512): cnt[96] + done ticket
}

__global__ __launch_bounds__(256) void k_collect(
        const float* __restrict__ yt0, const float* __restrict__ yt1,
        const float* __restrict__ yt2,
        int* __restrict__ cnt, float* __restrict__ tgt, int* __restrict__ tgtn) {
    int t = blockIdx.x * 256 + threadIdx.x;
    if (t >= TOTAL_CELLS) return;
    int s, local, G;
    const float* yt;
    if (t < C0)           { s = 0; local = t;           G = 13; yt = yt0; }
    else if (t < C0 + C1) { s = 1; local = t - C0;      G = 26; yt = yt1; }
    else                  { s = 2; local = t - C0 - C1; G = 52; yt = yt2; }
    int GG = G * G;
    int b  = local / (3 * GG);
    int n  = local - b * 3 * GG;          // b-relative flattened cell index
    int yidx = local * 85;
    float obj = yt[yidx + 4];
    if (obj > 0.5f) {
        int pos = atomicAdd(&cnt[s * 32 + b], 1);   // native int atomic
        if (pos < KMAX) {
            float4 box = make_float4(yt[yidx], yt[yidx + 1], yt[yidx + 2], yt[yidx + 3]);
            reinterpret_cast<float4*>(tgt)[(s * 32 + b) * KMAX + pos] = box;
            tgtn[(s * 32 + b) * KMAX + pos] = n;
        }
    }
}

// Fused: blocks [0,768)    = positive-slot losses, ONE SLOT PER WAVE (3072 slots);
//        blocks [768,2208) = conf loss over all cells (256 cells/block).
// Block partials -> part[bid]; last-finishing block (int ticket) reduces + emits out.
__global__ __launch_bounds__(256) void k_main(
        const float* __restrict__ fm0, const float* __restrict__ fm1,
        const float* __restrict__ fm2,
        const float* __restrict__ yt0, const float* __restrict__ yt1,
        const float* __restrict__ yt2,
        const float* __restrict__ anch,
        const int* __restrict__ cnt, const float* __restrict__ tgt,
        const int* __restrict__ tgtn,
        float* __restrict__ part, int* __restrict__ done,
        float* __restrict__ out) {
    __shared__ float  s_minx[KMAX], s_maxx[KMAX], s_miny[KMAX], s_maxy[KMAX], s_area[KMAX];
    __shared__ int    s_tn[KMAX];
    __shared__ int    s_cn;
    __shared__ float4 s_w[4];
    __shared__ int    s_last;

    int bid = blockIdx.x;
    int tid = threadIdx.x;
    int wid = tid >> 6, lane = tid & 63;

    float ax = 0.f, aw2 = 0.f, ap = 0.f, ac = 0.f;   // thread-local partials

    if (bid < NBLK_POS) {
        // ---- positive slots: slot = bid*4 + wid ----
        int slot = bid * 4 + wid;            // < 3072
        int sb = slot >> 5, idx = slot & 31;
        int s = sb >> 5, b = sb & 31;
        const float *fm, *yt;
        int G, anchoff;
        if (s == 0)      { fm = fm0; yt = yt0; G = 13; anchoff = 6; }
        else if (s == 1) { fm = fm1; yt = yt1; G = 26; anchoff = 3; }
        else             { fm = fm2; yt = yt2; G = 52; anchoff = 0; }
        int cn = min(cnt[sb], KMAX);
        if (idx < cn) {
            int GG = G * G;
            float stridef = IMGF / (float)G;
            float4 tb = reinterpret_cast<const float4*>(tgt)[sb * KMAX + idx];
            int n  = tgtn[sb * KMAX + idx];
            int a  = n % 3;
            int sp = n / 3;
            int jj = sp % G, ii = sp / G;
            int ybase = (b * 3 * GG + n) * 85;
            int fbase = (b * 255 + a * 85) * GG + sp;
            for (int c = lane; c < NCLS; c += 64) {      // class BCE, lane-parallel
                float pl  = fm[fbase + (5 + c) * GG];
                float tl  = yt[ybase + 5 + c];
                float lab = 0.99f * tl + 1.25e-4f;       // (1-delta)*t + delta/NC
                ap += bcef_(pl, lab);
            }
            if (lane == 0) {
                float p0 = fm[fbase];
                float p1 = fm[fbase + GG];
                float p2 = fm[fbase + 2 * GG];
                float p3 = fm[fbase + 3 * GG];
                float bcx = (sigmoidf_(p0) + (float)jj) * stridef;
                float bcy = (sigmoidf_(p1) + (float)ii) * stridef;
                float predx = bcx / stridef - (float)jj;
                float predy = bcy / stridef - (float)ii;
                float truex = tb.x / stridef - (float)jj;
                float truey = tb.y / stridef - (float)ii;
                float dx = truex - predx, dy = truey - predy;
                float bscale = 2.0f - (tb.z / IMGF) * (tb.w / IMGF);
                float aw = anch[(anchoff + a) * 2], ah = anch[(anchoff + a) * 2 + 1];
                float pw = expf(p2) * (aw / stridef) * stridef;
                float ph = expf(p3) * (ah / stridef) * stridef;
                float ptw = pw / aw, pth = ph / ah;
                float ttw = tb.z / aw, tth = tb.w / ah;
                ttw = (ttw == 0.0f) ? 1.0f : ttw;
                tth = (tth == 0.0f) ? 1.0f : tth;
                ptw = (ptw == 0.0f) ? 1.0f : ptw;
                pth = (pth == 0.0f) ? 1.0f : pth;
                ttw = logf(fminf(fmaxf(ttw, 1e-9f), 1e9f));
                tth = logf(fminf(fmaxf(tth, 1e-9f), 1e9f));
                ptw = logf(fminf(fmaxf(ptw, 1e-9f), 1e9f));
                pth = logf(fminf(fmaxf(pth, 1e-9f), 1e9f));
                float dw = ttw - ptw, dh = tth - pth;
                ax  += (dx * dx + dy * dy) * bscale;
                aw2 += (dw * dw + dh * dh) * bscale;
            }
        }
    } else {
        // ---- conf: 256 cells of one (scale,b,a) chunk ----
        int cb = bid - NBLK_POS;
        const float *fm;
        int G, chunks, s, anchoff;
        if (cb < 96)       { fm = fm0; G = 13; chunks = 1;  s = 0; anchoff = 6; }
        else if (cb < 384) { cb -= 96;  fm = fm1; G = 26; chunks = 3;  s = 1; anchoff = 3; }
        else               { cb -= 384; fm = fm2; G = 52; chunks = 11; s = 2; anchoff = 0; }
        int chunk = cb % chunks;
        int ba    = cb / chunks;
        int b = ba / 3, a = ba % 3;
        int GG = G * G;
        float stridef = IMGF / (float)G;
        int sb = s * 32 + b;
        if (tid == 0) s_cn = min(cnt[sb], KMAX);
        if (tid < KMAX) {
            float4 tb = reinterpret_cast<const float4*>(tgt)[sb * KMAX + tid];
            s_minx[tid] = tb.x - tb.z * 0.5f;
            s_maxx[tid] = tb.x + tb.z * 0.5f;
            s_miny[tid] = tb.y - tb.w * 0.5f;
            s_maxy[tid] = tb.y + tb.w * 0.5f;
            s_area[tid] = tb.z * tb.w;
            s_tn[tid]   = tgtn[sb * KMAX + tid];
        }
        __syncthreads();
        int sp = chunk * 256 + tid;
        if (sp < GG) {
            int jj = sp % G, ii = sp / G;
            int n = sp * 3 + a;
            int fbase = (b * 255 + a * 85) * GG + sp;
            float p0 = fm[fbase];
            float p1 = fm[fbase + GG];
            float p2 = fm[fbase + 2 * GG];
            float p3 = fm[fbase + 3 * GG];
            float p4 = fm[fbase + 4 * GG];
            float aw = anch[(anchoff + a) * 2], ah = anch[(anchoff + a) * 2 + 1];
            float cx = (sigmoidf_(p0) + (float)jj) * stridef;
            float cy = (sigmoidf_(p1) + (float)ii) * stridef;
            float pw = expf(p2) * (aw / stridef) * stridef;
            float ph = expf(p3) * (ah / stridef) * stridef;
            float pminx = cx - pw * 0.5f, pmaxx = cx + pw * 0.5f;
            float pminy = cy - ph * 0.5f, pmaxy = cy + ph * 0.5f;
            float parea = pw * ph;
            int cn = s_cn;
            float best = 0.0f, m = 0.0f;
            for (int k = 0; k < cn; ++k) {
                if (s_tn[k] == n) m = 1.0f;
                float iw = fminf(pmaxx, s_maxx[k]) - fmaxf(pminx, s_minx[k]);
                float ih = fminf(pmaxy, s_maxy[k]) - fmaxf(pminy, s_miny[k]);
                iw = fmaxf(iw, 0.0f);
                ih = fmaxf(ih, 0.0f);
                float inter = iw * ih;
                float iou = inter / ((parea + s_area[k] - inter) + 1e-10f);
                best = fmaxf(best, iou);
            }
            float ign = (cn > 0 && best < 0.5f) ? 1.0f : 0.0f;
            float bce = bcef_(p4, m);
            float d = fabsf(m - sigmoidf_(p4));
            ac += (m * bce + 0.5f * (1.0f - m) * ign * bce) * (d * d);
        }
    }

    // ---- block reduction of (ax, aw2, ap, ac) ----
    for (int off = 32; off; off >>= 1) {
        ax  += __shfl_down(ax,  off);
        aw2 += __shfl_down(aw2, off);
        ap  += __shfl_down(ap,  off);
        ac  += __shfl_down(ac,  off);
    }
    if (lane == 0) s_w[wid] = make_float4(ax, aw2, ap, ac);
    __syncthreads();
    if (tid == 0) {
        float4 r0 = s_w[0], r1 = s_w[1], r2 = s_w[2], r3 = s_w[3];
        reinterpret_cast<float4*>(part)[bid] =
            make_float4(r0.x + r1.x + r2.x + r3.x,
                        r0.y + r1.y + r2.y + r3.y,
                        r0.z + r1.z + r2.z + r3.z,
                        r0.w + r1.w + r2.w + r3.w);
        __threadfence();                     // part[bid] visible at agent scope
        int prev = atomicAdd(done, 1);       // native int atomic
        s_last = (prev == NBLK_MAIN - 1) ? 1 : 0;
    }
    __syncthreads();

    // ---- last-finishing block: final reduce + output ----
    if (s_last) {
        double dx = 0.0, dw = 0.0, dp = 0.0, dc = 0.0;
        for (int i = tid; i < NBLK_MAIN; i += 256) {
            const float* pp = part + (size_t)i * 4;
            dx += (double)aload_f(pp);       // agent loads: bypass stale local L2
            dw += (double)aload_f(pp + 1);
            dp += (double)aload_f(pp + 2);
            dc += (double)aload_f(pp + 3);
        }
        for (int off = 32; off; off >>= 1) {
            dx += __shfl_down(dx, off);
            dw += __shfl_down(dw, off);
            dp += __shfl_down(dp, off);
            dc += __shfl_down(dc, off);
        }
        __shared__ double sd[4][4];
        if (lane == 0) { sd[wid][0] = dx; sd[wid][1] = dw; sd[wid][2] = dp; sd[wid][3] = dc; }
        __syncthreads();
        if (tid == 0) {
            double X = sd[0][0] + sd[1][0] + sd[2][0] + sd[3][0];
            double W = sd[0][1] + sd[1][1] + sd[2][1] + sd[3][1];
            double P = sd[0][2] + sd[1][2] + sd[2][2] + sd[3][2];
            double C = sd[0][3] + sd[1][3] + sd[2][3] + sd[3][3];
            double xy = 5.0 * X / 32.0;
            double wh = 5.0 * W / 32.0;
            double cf = C / 32.0;
            double pb = P / 32.0;
            out[0] = (float)(xy + wh + cf + pb);
            out[1] = (float)xy;
            out[2] = (float)wh;
            out[3] = (float)cf;
            out[4] = (float)pb;
        }
    }
}

extern "C" void kernel_launch(void* const* d_in, const int* in_sizes, int n_in,
                              void* d_out, int out_size, void* d_ws, size_t ws_size,
                              hipStream_t stream) {
    const float* fm0  = (const float*)d_in[0];
    const float* yt0  = (const float*)d_in[1];
    const float* fm1  = (const float*)d_in[2];
    const float* yt1  = (const float*)d_in[3];
    const float* fm2  = (const float*)d_in[4];
    const float* yt2  = (const float*)d_in[5];
    const float* anch = (const float*)d_in[6];
    float* out = (float*)d_out;

    char* ws = (char*)d_ws;
    int*   cnt  = (int*)(ws + OFF_CNT);
    int*   done = (int*)(ws + OFF_DONE);
    float* part = (float*)(ws + OFF_PART);
    float* tgt  = (float*)(ws + OFF_TGT);
    int*   tgtn = (int*)(ws + OFF_TGTN);

    k_init<<<1, 128, 0, stream>>>((int*)ws);
    k_collect<<<(TOTAL_CELLS + 255) / 256, 256, 0, stream>>>(
        yt0, yt1, yt2, cnt, tgt, tgtn);
    k_main<<<NBLK_MAIN, 256, 0, stream>>>(
        fm0, fm1, fm2, yt0, yt1, yt2, anch, cnt, tgt, tgtn, part, done, out);
}

// Round 7
// 35.400 us; speedup vs baseline: 3.4835x; 2.1682x over previous
//
#include <hip/hip_runtime.h>
#include <math.h>

// YOLO loss, 3 scales: G in {13,26,52}, B=32, A=3, 85 ch (5+80), IMG=416.
// Inputs (setup_inputs dict order): fm0, yt0, fm1, yt1, fm2, yt2, anchors(9x2)
// Output: 5 floats: total, xy, wh, conf, prob
//
// Hard-won notes (MI355X):
//  - hipcc lowers atomicAdd(float/double) on global to CAS loops. Contended fp
//    atomics serialize ~40ns/success -> NEVER use them.
//  - Per-block __threadfence()+ticket finalize costs ~20-40ns x blocks at the
//    coherence point: at 2208 blocks that was +40us (R6). Plain-store partials
//    + separate 1-block reduce dispatch wins.
//  - Intra-kernel grid barriers need co-residency caps that starve latency-
//    bound phases of TLP (R5: 123us). Separate dispatches win.
//  - This version: ZERO atomics, ZERO fences, 3 dispatches. Collect uses
//    per-(s,b,range) ordered ballot compaction -> deterministic, no init pass.

constexpr int   NCLS  = 80;
constexpr int   PMAX  = 4;     // max sub-lists per (s,b): s0:1, s1:2, s2:4
constexpr int   SLOTS = 32;    // capacity per sub-list (<=20 positives/(s,b) total)
constexpr float IMGF  = 416.0f;

constexpr int NBLK_COLLECT = 32 * (1 + 2 + 4);   // 224
constexpr int NBLK_POS  = 768;                   // 4 waves/blk, 1 slot/wave = 3072 slots
constexpr int NBLK_CONF = 96 + 288 + 1056;       // 1440
constexpr int NBLK_MAIN = NBLK_POS + NBLK_CONF;  // 2208

// ws layout (every consumed byte rewritten every call; no atomics anywhere):
constexpr size_t OFF_CNT  = 0;                                    // int cnt[96][4]
constexpr size_t OFF_PART = 1536;                                 // float4 part[2208]
constexpr size_t OFF_TGT  = OFF_PART + (size_t)NBLK_MAIN * 16;    // 36864: float4 tgt[96][4][32]
constexpr size_t OFF_TGTN = OFF_TGT + (size_t)96 * PMAX * SLOTS * 16; // 233472: int tgtn[96][4][32]
// end = 282624 bytes

__device__ inline float sigmoidf_(float x) { return 1.0f / (1.0f + expf(-x)); }
__device__ inline float bcef_(float l, float t) {
    return fmaxf(l, 0.0f) - l * t + log1pf(expf(-fabsf(l)));
}

// One block per (scale, b, range-part). Ordered ballot compaction, plain stores.
__global__ __launch_bounds__(512) void k_collect(
        const float* __restrict__ yt0, const float* __restrict__ yt1,
        const float* __restrict__ yt2,
        int* __restrict__ cnt, float* __restrict__ tgt, int* __restrict__ tgtn) {
    int bid = blockIdx.x, tid = threadIdx.x;
    int lane = tid & 63, wid = tid >> 6;
    int s, b, p, P, G;
    const float* yt;
    if (bid < 32)      { s = 0; b = bid;            p = 0;       P = 1; yt = yt0; G = 13; }
    else if (bid < 96) { s = 1; int i = bid - 32; b = i >> 1; p = i & 1; P = 2; yt = yt1; G = 26; }
    else               { s = 2; int i = bid - 96; b = i >> 2; p = i & 3; P = 4; yt = yt2; G = 52; }
    int GG3  = 3 * G * G;
    int per  = (GG3 + P - 1) / P;              // 507 / 1014 / 2028
    int nbase = p * per;
    int count = min(per, GG3 - nbase);
    int nit  = (count + 511) / 512;            // 1 / 2 / 4
    int sb = s * 32 + b;

    __shared__ int s_wcnt[8];
    __shared__ int s_base;
    if (tid == 0) s_base = 0;

    // prefetch obj for all iterations (latency overlap)
    float obj[4];
    int   nn[4];
    #pragma unroll
    for (int it = 0; it < 4; ++it) {
        int c = it * 512 + tid;
        nn[it]  = nbase + c;
        obj[it] = 0.0f;
        if (c < count) obj[it] = yt[(size_t)(b * GG3 + nn[it]) * 85 + 4];
    }
    __syncthreads();

    for (int it = 0; it < nit; ++it) {
        bool pos = obj[it] > 0.5f;
        unsigned long long mask = __ballot(pos);
        if (lane == 0) s_wcnt[wid] = __popcll(mask);
        __syncthreads();
        int wpre = 0, tot = 0;
        #pragma unroll
        for (int w = 0; w < 8; ++w) { if (w < wid) wpre += s_wcnt[w]; tot += s_wcnt[w]; }
        int rank = s_base + wpre + (int)__popcll(mask & ((1ull << lane) - 1ull));
        if (pos && rank < SLOTS) {
            size_t yb = (size_t)(b * GG3 + nn[it]) * 85;
            int slot = (sb * PMAX + p) * SLOTS + rank;
            float4 box = make_float4(yt[yb], yt[yb + 1], yt[yb + 2], yt[yb + 3]);
            reinterpret_cast<float4*>(tgt)[slot] = box;
            tgtn[slot] = nn[it];
        }
        __syncthreads();
        if (tid == 0) s_base += tot;
        __syncthreads();
    }
    if (tid == 0) {
        cnt[sb * PMAX + p] = min(s_base, SLOTS);
        if (p == 0)                                  // zero-fill unused sub-list counts
            for (int q = P; q < PMAX; ++q) cnt[sb * PMAX + q] = 0;
    }
}

// Fused: blocks [0,768)    = positive-slot losses, ONE SLOT PER WAVE (3072 slots);
//        blocks [768,2208) = conf loss over all cells (256 cells/block).
// Every block writes part[bid] with a plain store. No atomics, no fences.
__global__ __launch_bounds__(256) void k_main(
        const float* __restrict__ fm0, const float* __restrict__ fm1,
        const float* __restrict__ fm2,
        const float* __restrict__ yt0, const float* __restrict__ yt1,
        const float* __restrict__ yt2,
        const float* __restrict__ anch,
        const int* __restrict__ cnt, const float* __restrict__ tgt,
        const int* __restrict__ tgtn, float4* __restrict__ part) {
    __shared__ float  s_minx[128], s_maxx[128], s_miny[128], s_maxy[128], s_area[128];
    __shared__ int    s_tn[128];
    __shared__ int    s_cn4[4];
    __shared__ float4 s_w[4];

    int bid = blockIdx.x;
    int tid = threadIdx.x;
    int wid = tid >> 6, lane = tid & 63;

    float ax = 0.f, aw2 = 0.f, ap = 0.f, ac = 0.f;

    if (bid < NBLK_POS) {
        // ---- positive slots: slot = bid*4 + wid ----
        int slot = bid * 4 + wid;            // < 3072
        int sb = slot >> 5, idx = slot & 31;
        int s = sb >> 5, b = sb & 31;
        const float *fm, *yt;
        int G, anchoff;
        if (s == 0)      { fm = fm0; yt = yt0; G = 13; anchoff = 6; }
        else if (s == 1) { fm = fm1; yt = yt1; G = 26; anchoff = 3; }
        else             { fm = fm2; yt = yt2; G = 52; anchoff = 0; }
        int c0 = cnt[sb * PMAX + 0], c1 = cnt[sb * PMAX + 1];
        int c2 = cnt[sb * PMAX + 2], c3 = cnt[sb * PMAX + 3];
        int cn_total = c0 + c1 + c2 + c3;
        if (idx < cn_total) {
            int p = 0, rem = idx;                // locate sub-list (uniform per wave)
            if (rem >= c0) { rem -= c0; p = 1;
                if (rem >= c1) { rem -= c1; p = 2;
                    if (rem >= c2) { rem -= c2; p = 3; } } }
            int entry = (sb * PMAX + p) * SLOTS + rem;
            int GG = G * G;
            float stridef = IMGF / (float)G;
            float4 tb = reinterpret_cast<const float4*>(tgt)[entry];
            int n  = tgtn[entry];
            int a  = n % 3;
            int sp = n / 3;
            int jj = sp % G, ii = sp / G;
            int ybase = (b * 3 * GG + n) * 85;
            int fbase = (b * 255 + a * 85) * GG + sp;
            for (int c = lane; c < NCLS; c += 64) {      // class BCE, lane-parallel
                float pl  = fm[fbase + (5 + c) * GG];
                float tl  = yt[ybase + 5 + c];
                float lab = 0.99f * tl + 1.25e-4f;       // (1-delta)*t + delta/NC
                ap += bcef_(pl, lab);
            }
            if (lane == 0) {
                float p0 = fm[fbase];
                float p1 = fm[fbase + GG];
                float p2 = fm[fbase + 2 * GG];
                float p3 = fm[fbase + 3 * GG];
                float bcx = (sigmoidf_(p0) + (float)jj) * stridef;
                float bcy = (sigmoidf_(p1) + (float)ii) * stridef;
                float predx = bcx / stridef - (float)jj;
                float predy = bcy / stridef - (float)ii;
                float truex = tb.x / stridef - (float)jj;
                float truey = tb.y / stridef - (float)ii;
                float dx = truex - predx, dy = truey - predy;
                float bscale = 2.0f - (tb.z / IMGF) * (tb.w / IMGF);
                float aw = anch[(anchoff + a) * 2], ah = anch[(anchoff + a) * 2 + 1];
                float pw = expf(p2) * (aw / stridef) * stridef;
                float ph = expf(p3) * (ah / stridef) * stridef;
                float ptw = pw / aw, pth = ph / ah;
                float ttw = tb.z / aw, tth = tb.w / ah;
                ttw = (ttw == 0.0f) ? 1.0f : ttw;
                tth = (tth == 0.0f) ? 1.0f : tth;
                ptw = (ptw == 0.0f) ? 1.0f : ptw;
                pth = (pth == 0.0f) ? 1.0f : pth;
                ttw = logf(fminf(fmaxf(ttw, 1e-9f), 1e9f));
                tth = logf(fminf(fmaxf(tth, 1e-9f), 1e9f));
                ptw = logf(fminf(fmaxf(ptw, 1e-9f), 1e9f));
                pth = logf(fminf(fmaxf(pth, 1e-9f), 1e9f));
                float dw = ttw - ptw, dh = tth - pth;
                ax  += (dx * dx + dy * dy) * bscale;
                aw2 += (dw * dw + dh * dh) * bscale;
            }
        }
    } else {
        // ---- conf: 256 cells of one (scale,b,a) chunk ----
        int cb = bid - NBLK_POS;
        const float *fm;
        int G, chunks, s, anchoff;
        if (cb < 96)       { fm = fm0; G = 13; chunks = 1;  s = 0; anchoff = 6; }
        else if (cb < 384) { cb -= 96;  fm = fm1; G = 26; chunks = 3;  s = 1; anchoff = 3; }
        else               { cb -= 384; fm = fm2; G = 52; chunks = 11; s = 2; anchoff = 0; }
        int chunk = cb % chunks;
        int ba    = cb / chunks;
        int b = ba / 3, a = ba % 3;
        int GG = G * G;
        float stridef = IMGF / (float)G;
        int sb = s * 32 + b;
        if (tid < 4) s_cn4[tid] = cnt[sb * PMAX + tid];
        if (tid < 128) {                       // stage all 4 sub-lists (128 slots)
            int slot = sb * PMAX * SLOTS + tid;
            float4 tb = reinterpret_cast<const float4*>(tgt)[slot];
            s_minx[tid] = tb.x - tb.z * 0.5f;
            s_maxx[tid] = tb.x + tb.z * 0.5f;
            s_miny[tid] = tb.y - tb.w * 0.5f;
            s_maxy[tid] = tb.y + tb.w * 0.5f;
            s_area[tid] = tb.z * tb.w;
            s_tn[tid]   = tgtn[slot];
        }
        __syncthreads();
        int sp = chunk * 256 + tid;
        if (sp < GG) {
            int jj = sp % G, ii = sp / G;
            int n = sp * 3 + a;
            int fbase = (b * 255 + a * 85) * GG + sp;
            float p0 = fm[fbase];
            float p1 = fm[fbase + GG];
            float p2 = fm[fbase + 2 * GG];
            float p3 = fm[fbase + 3 * GG];
            float p4 = fm[fbase + 4 * GG];
            float aw = anch[(anchoff + a) * 2], ah = anch[(anchoff + a) * 2 + 1];
            float cx = (sigmoidf_(p0) + (float)jj) * stridef;
            float cy = (sigmoidf_(p1) + (float)ii) * stridef;
            float pw = expf(p2) * (aw / stridef) * stridef;
            float ph = expf(p3) * (ah / stridef) * stridef;
            float pminx = cx - pw * 0.5f, pmaxx = cx + pw * 0.5f;
            float pminy = cy - ph * 0.5f, pmaxy = cy + ph * 0.5f;
            float parea = pw * ph;
            float best = 0.0f, m = 0.0f;
            int cn_total = 0;
            #pragma unroll
            for (int p = 0; p < PMAX; ++p) {
                int cnp = s_cn4[p];
                cn_total += cnp;
                for (int k = 0; k < cnp; ++k) {
                    int e = p * SLOTS + k;
                    if (s_tn[e] == n) m = 1.0f;
                    float iw = fminf(pmaxx, s_maxx[e]) - fmaxf(pminx, s_minx[e]);
                    float ih = fminf(pmaxy, s_maxy[e]) - fmaxf(pminy, s_miny[e]);
                    iw = fmaxf(iw, 0.0f);
                    ih = fmaxf(ih, 0.0f);
                    float inter = iw * ih;
                    float iou = inter / ((parea + s_area[e] - inter) + 1e-10f);
                    best = fmaxf(best, iou);
                }
            }
            float ign = (cn_total > 0 && best < 0.5f) ? 1.0f : 0.0f;
            float bce = bcef_(p4, m);
            float d = fabsf(m - sigmoidf_(p4));
            ac += (m * bce + 0.5f * (1.0f - m) * ign * bce) * (d * d);
        }
    }

    // ---- block reduction of (ax, aw2, ap, ac); plain store of partial ----
    for (int off = 32; off; off >>= 1) {
        ax  += __shfl_down(ax,  off);
        aw2 += __shfl_down(aw2, off);
        ap  += __shfl_down(ap,  off);
        ac  += __shfl_down(ac,  off);
    }
    if (lane == 0) s_w[wid] = make_float4(ax, aw2, ap, ac);
    __syncthreads();
    if (tid == 0) {
        float4 r0 = s_w[0], r1 = s_w[1], r2 = s_w[2], r3 = s_w[3];
        part[bid] = make_float4(r0.x + r1.x + r2.x + r3.x,
                                r0.y + r1.y + r2.y + r3.y,
                                r0.z + r1.z + r2.z + r3.z,
                                r0.w + r1.w + r2.w + r3.w);
    }
}

// Sum the 2208 per-block partials (double accumulation) and emit the 5 outputs.
__global__ __launch_bounds__(512) void k_reduce(
        const float4* __restrict__ part, float* __restrict__ out) {
    int t = threadIdx.x;
    double x = 0.0, w = 0.0, p = 0.0, c = 0.0;
    for (int i = t; i < NBLK_MAIN; i += 512) {
        float4 v = part[i];
        x += (double)v.x; w += (double)v.y; p += (double)v.z; c += (double)v.w;
    }
    for (int off = 32; off; off >>= 1) {
        x += __shfl_down(x, off);
        w += __shfl_down(w, off);
        p += __shfl_down(p, off);
        c += __shfl_down(c, off);
    }
    __shared__ double sx[8], sw[8], sp[8], sc[8];
    int wid = t >> 6, lane = t & 63;
    if (lane == 0) { sx[wid] = x; sw[wid] = w; sp[wid] = p; sc[wid] = c; }
    __syncthreads();
    if (t == 0) {
        double X = 0, W = 0, P = 0, C = 0;
        for (int i = 0; i < 8; ++i) { X += sx[i]; W += sw[i]; P += sp[i]; C += sc[i]; }
        double xy = 5.0 * X / 32.0;
        double wh = 5.0 * W / 32.0;
        double cf = C / 32.0;
        double pb = P / 32.0;
        out[0] = (float)(xy + wh + cf + pb);
        out[1] = (float)xy;
        out[2] = (float)wh;
        out[3] = (float)cf;
        out[4] = (float)pb;
    }
}

extern "C" void kernel_launch(void* const* d_in, const int* in_sizes, int n_in,
                              void* d_out, int out_size, void* d_ws, size_t ws_size,
                              hipStream_t stream) {
    const float* fm0  = (const float*)d_in[0];
    const float* yt0  = (const float*)d_in[1];
    const float* fm1  = (const float*)d_in[2];
    const float* yt1  = (const float*)d_in[3];
    const float* fm2  = (const float*)d_in[4];
    const float* yt2  = (const float*)d_in[5];
    const float* anch = (const float*)d_in[6];
    float* out = (float*)d_out;

    char* ws = (char*)d_ws;
    int*    cnt  = (int*)(ws + OFF_CNT);
    float4* part = (float4*)(ws + OFF_PART);
    float*  tgt  = (float*)(ws + OFF_TGT);
    int*    tgtn = (int*)(ws + OFF_TGTN);

    k_collect<<<NBLK_COLLECT, 512, 0, stream>>>(yt0, yt1, yt2, cnt, tgt, tgtn);
    k_main<<<NBLK_MAIN, 256, 0, stream>>>(
        fm0, fm1, fm2, yt0, yt1, yt2, anch, cnt, tgt, tgtn, part);
    k_reduce<<<1, 512, 0, stream>>>(part, out);
}

// Round 8
// 34.448 us; speedup vs baseline: 3.5797x; 1.0276x over previous
//
#include <hip/hip_runtime.h>
#include <math.h>

// YOLO loss, 3 scales: G in {13,26,52}, B=32, A=3, 85 ch (5+80), IMG=416.
// Inputs (setup_inputs dict order): fm0, yt0, fm1, yt1, fm2, yt2, anchors(9x2)
// Output: 5 floats: total, xy, wh, conf, prob
//
// Hard-won notes (MI355X):
//  - hipcc lowers atomicAdd(float/double) on global to CAS loops. Contended fp
//    atomics serialize ~40ns/success -> NEVER use them.
//  - ANY per-block same-address serialization (fp CAS, threadfence+int ticket)
//    costs ~18-40ns x blocks at the coherence point: 2208 blocks = +40us (R6).
//    Plain-store partials + separate 1-block reduce dispatch wins.
//  - Intra-kernel grid barriers need co-residency caps that starve latency-
//    bound phases of TLP (R5: 123us). Separate dispatches win.
//  - Positive-cell losses are self-contained per collect sub-list -> computed
//    inside k_collect (targets already in LDS; gathers hide under obj-gather
//    latency). k_main is pure streaming conf.
//  - ZERO atomics, ZERO fences, 3 dispatches.

constexpr int   NCLS  = 80;
constexpr int   PMAX  = 4;     // sub-lists per (s,b): s0:1, s1:2, s2:4
constexpr int   SLOTS = 32;    // capacity per sub-list (<=20 positives/(s,b))
constexpr float IMGF  = 416.0f;

constexpr int NBLK_COLLECT = 32 * (1 + 2 + 4);   // 224
constexpr int NBLK_CONF    = 96 + 288 + 1056;    // 1440
constexpr int NPART        = NBLK_COLLECT + NBLK_CONF;  // 1664

// ws layout (every consumed byte rewritten every call):
constexpr size_t OFF_CNT  = 0;                                    // int cnt[96][4]
constexpr size_t OFF_PART = 1536;                                 // float4 part[1664]
constexpr size_t OFF_TGT  = OFF_PART + (size_t)NPART * 16;        // float4 tgt[96][4][32]
constexpr size_t OFF_TGTN = OFF_TGT + (size_t)96 * PMAX * SLOTS * 16; // int tgtn[96][4][32]

__device__ inline float sigmoidf_(float x) { return 1.0f / (1.0f + expf(-x)); }
__device__ inline float bcef_(float l, float t) {
    return fmaxf(l, 0.0f) - l * t + log1pf(expf(-fabsf(l)));
}

// One block per (scale, b, range-part). Ordered ballot compaction (plain
// stores), then pos losses for the block's own slots (one slot per wave).
__global__ __launch_bounds__(512) void k_collect(
        const float* __restrict__ fm0, const float* __restrict__ fm1,
        const float* __restrict__ fm2,
        const float* __restrict__ yt0, const float* __restrict__ yt1,
        const float* __restrict__ yt2,
        const float* __restrict__ anch,
        int* __restrict__ cnt, float* __restrict__ tgt, int* __restrict__ tgtn,
        float4* __restrict__ part) {
    int bid = blockIdx.x, tid = threadIdx.x;
    int lane = tid & 63, wid = tid >> 6;
    int s, b, p, P, G;
    const float *yt, *fm;
    int anchoff;
    if (bid < 32)      { s = 0; b = bid;          p = 0;       P = 1; yt = yt0; fm = fm0; G = 13; anchoff = 6; }
    else if (bid < 96) { s = 1; int i = bid - 32; b = i >> 1; p = i & 1; P = 2; yt = yt1; fm = fm1; G = 26; anchoff = 3; }
    else               { s = 2; int i = bid - 96; b = i >> 2; p = i & 3; P = 4; yt = yt2; fm = fm2; G = 52; anchoff = 0; }
    int GG   = G * G;
    int GG3  = 3 * GG;
    int per  = (GG3 + P - 1) / P;              // 507 / 1014 / 2028
    int nbase = p * per;
    int count = min(per, GG3 - nbase);
    int nit  = (count + 511) / 512;            // 1 / 2 / 4
    int sb = s * 32 + b;
    float stridef = IMGF / (float)G;

    __shared__ int    s_wcnt[8];
    __shared__ int    s_base;
    __shared__ int    s_n[SLOTS];
    __shared__ float4 s_box[SLOTS];
    __shared__ float4 s_pw[8];
    if (tid == 0) s_base = 0;

    // prefetch obj for all iterations (latency overlap)
    float obj[4];
    int   nn[4];
    #pragma unroll
    for (int it = 0; it < 4; ++it) {
        int c = it * 512 + tid;
        nn[it]  = nbase + c;
        obj[it] = 0.0f;
        if (c < count) obj[it] = yt[(size_t)(b * GG3 + nn[it]) * 85 + 4];
    }
    __syncthreads();

    for (int it = 0; it < nit; ++it) {
        bool pos = obj[it] > 0.5f;
        unsigned long long mask = __ballot(pos);
        if (lane == 0) s_wcnt[wid] = __popcll(mask);
        __syncthreads();
        int wpre = 0, tot = 0;
        #pragma unroll
        for (int w = 0; w < 8; ++w) { if (w < wid) wpre += s_wcnt[w]; tot += s_wcnt[w]; }
        int rank = s_base + wpre + (int)__popcll(mask & ((1ull << lane) - 1ull));
        if (pos && rank < SLOTS) {
            size_t yb = (size_t)(b * GG3 + nn[it]) * 85;
            int slot = (sb * PMAX + p) * SLOTS + rank;
            float4 box = make_float4(yt[yb], yt[yb + 1], yt[yb + 2], yt[yb + 3]);
            reinterpret_cast<float4*>(tgt)[slot] = box;   // for k_conf
            tgtn[slot] = nn[it];
            s_box[rank] = box;                            // for this block's pos pass
            s_n[rank]   = nn[it];
        }
        __syncthreads();
        if (tid == 0) s_base += tot;
        __syncthreads();
    }
    int cn = min(s_base, SLOTS);
    if (tid == 0) {
        cnt[sb * PMAX + p] = cn;
        if (p == 0)                                  // zero unused sub-list counts
            for (int q = P; q < PMAX; ++q) cnt[sb * PMAX + q] = 0;
    }

    // ---- pos losses for this block's slots: one slot per wave ----
    float ax = 0.f, aw2 = 0.f, ap = 0.f;
    for (int slot = wid; slot < cn; slot += 8) {
        float4 tb = s_box[slot];
        int n  = s_n[slot];
        int a  = n % 3;
        int sp = n / 3;
        int jj = sp % G, ii = sp / G;
        int ybase = (b * GG3 + n) * 85;
        int fbase = (b * 255 + a * 85) * GG + sp;
        for (int c = lane; c < NCLS; c += 64) {      // class BCE, lane-parallel
            float pl  = fm[fbase + (5 + c) * GG];
            float tl  = yt[ybase + 5 + c];
            float lab = 0.99f * tl + 1.25e-4f;       // (1-delta)*t + delta/NC
            ap += bcef_(pl, lab);
        }
        if (lane == 0) {
            float p0 = fm[fbase];
            float p1 = fm[fbase + GG];
            float p2 = fm[fbase + 2 * GG];
            float p3 = fm[fbase + 3 * GG];
            float bcx = (sigmoidf_(p0) + (float)jj) * stridef;
            float bcy = (sigmoidf_(p1) + (float)ii) * stridef;
            float predx = bcx / stridef - (float)jj;
            float predy = bcy / stridef - (float)ii;
            float truex = tb.x / stridef - (float)jj;
            float truey = tb.y / stridef - (float)ii;
            float dx = truex - predx, dy = truey - predy;
            float bscale = 2.0f - (tb.z / IMGF) * (tb.w / IMGF);
            float aw = anch[(anchoff + a) * 2], ah = anch[(anchoff + a) * 2 + 1];
            float pw = expf(p2) * (aw / stridef) * stridef;
            float ph = expf(p3) * (ah / stridef) * stridef;
            float ptw = pw / aw, pth = ph / ah;
            float ttw = tb.z / aw, tth = tb.w / ah;
            ttw = (ttw == 0.0f) ? 1.0f : ttw;
            tth = (tth == 0.0f) ? 1.0f : tth;
            ptw = (ptw == 0.0f) ? 1.0f : ptw;
            pth = (pth == 0.0f) ? 1.0f : pth;
            ttw = logf(fminf(fmaxf(ttw, 1e-9f), 1e9f));
            tth = logf(fminf(fmaxf(tth, 1e-9f), 1e9f));
            ptw = logf(fminf(fmaxf(ptw, 1e-9f), 1e9f));
            pth = logf(fminf(fmaxf(pth, 1e-9f), 1e9f));
            float dw = ttw - ptw, dh = tth - pth;
            ax  += (dx * dx + dy * dy) * bscale;
            aw2 += (dw * dw + dh * dh) * bscale;
        }
    }
    // wave-ordered deterministic reduction
    for (int off = 32; off; off >>= 1) ap += __shfl_down(ap, off);
    if (lane == 0) s_pw[wid] = make_float4(ax, aw2, ap, 0.f);
    __syncthreads();
    if (tid == 0) {
        float X = 0.f, W = 0.f, Pp = 0.f;
        #pragma unroll
        for (int w = 0; w < 8; ++w) { X += s_pw[w].x; W += s_pw[w].y; Pp += s_pw[w].z; }
        part[bid] = make_float4(X, W, Pp, 0.f);
    }
}

// Pure conf loss: 1440 blocks x 256, 256 cells of one (scale,b,a) chunk each.
__global__ __launch_bounds__(256) void k_conf(
        const float* __restrict__ fm0, const float* __restrict__ fm1,
        const float* __restrict__ fm2,
        const float* __restrict__ anch,
        const int* __restrict__ cnt, const float* __restrict__ tgt,
        const int* __restrict__ tgtn, float4* __restrict__ part) {
    __shared__ float  s_minx[128], s_maxx[128], s_miny[128], s_maxy[128], s_area[128];
    __shared__ int    s_tn[128];
    __shared__ int    s_cn4[4];
    __shared__ float  s_w1[4];

    int bid = blockIdx.x;
    int tid = threadIdx.x;
    int wid = tid >> 6, lane = tid & 63;

    int cb = bid;
    const float *fm;
    int G, chunks, s, anchoff;
    if (cb < 96)       { fm = fm0; G = 13; chunks = 1;  s = 0; anchoff = 6; }
    else if (cb < 384) { cb -= 96;  fm = fm1; G = 26; chunks = 3;  s = 1; anchoff = 3; }
    else               { cb -= 384; fm = fm2; G = 52; chunks = 11; s = 2; anchoff = 0; }
    int chunk = cb % chunks;
    int ba    = cb / chunks;
    int b = ba / 3, a = ba % 3;
    int GG = G * G;
    float stridef = IMGF / (float)G;
    int sb = s * 32 + b;
    if (tid < 4) s_cn4[tid] = cnt[sb * PMAX + tid];
    if (tid < 128) {                       // stage all 4 sub-lists (128 slots)
        int slot = sb * PMAX * SLOTS + tid;
        float4 tb = reinterpret_cast<const float4*>(tgt)[slot];
        s_minx[tid] = tb.x - tb.z * 0.5f;
        s_maxx[tid] = tb.x + tb.z * 0.5f;
        s_miny[tid] = tb.y - tb.w * 0.5f;
        s_maxy[tid] = tb.y + tb.w * 0.5f;
        s_area[tid] = tb.z * tb.w;
        s_tn[tid]   = tgtn[slot];
    }
    __syncthreads();

    float ac = 0.f;
    int sp = chunk * 256 + tid;
    if (sp < GG) {
        int jj = sp % G, ii = sp / G;
        int n = sp * 3 + a;
        int fbase = (b * 255 + a * 85) * GG + sp;
        float p0 = fm[fbase];
        float p1 = fm[fbase + GG];
        float p2 = fm[fbase + 2 * GG];
        float p3 = fm[fbase + 3 * GG];
        float p4 = fm[fbase + 4 * GG];
        float aw = anch[(anchoff + a) * 2], ah = anch[(anchoff + a) * 2 + 1];
        float cx = (sigmoidf_(p0) + (float)jj) * stridef;
        float cy = (sigmoidf_(p1) + (float)ii) * stridef;
        float pw = expf(p2) * (aw / stridef) * stridef;
        float ph = expf(p3) * (ah / stridef) * stridef;
        float pminx = cx - pw * 0.5f, pmaxx = cx + pw * 0.5f;
        float pminy = cy - ph * 0.5f, pmaxy = cy + ph * 0.5f;
        float parea = pw * ph;
        float best = 0.0f, m = 0.0f;
        int cn_total = 0;
        #pragma unroll
        for (int pp = 0; pp < PMAX; ++pp) {
            int cnp = s_cn4[pp];
            cn_total += cnp;
            for (int k = 0; k < cnp; ++k) {
                int e = pp * SLOTS + k;
                if (s_tn[e] == n) m = 1.0f;
                float iw = fminf(pmaxx, s_maxx[e]) - fmaxf(pminx, s_minx[e]);
                float ih = fminf(pmaxy, s_maxy[e]) - fmaxf(pminy, s_miny[e]);
                iw = fmaxf(iw, 0.0f);
                ih = fmaxf(ih, 0.0f);
                float inter = iw * ih;
                float iou = inter / ((parea + s_area[e] - inter) + 1e-10f);
                best = fmaxf(best, iou);
            }
        }
        float ign = (cn_total > 0 && best < 0.5f) ? 1.0f : 0.0f;
        float bce = bcef_(p4, m);
        float d = fabsf(m - sigmoidf_(p4));
        ac = (m * bce + 0.5f * (1.0f - m) * ign * bce) * (d * d);
    }

    for (int off = 32; off; off >>= 1) ac += __shfl_down(ac, off);
    if (lane == 0) s_w1[wid] = ac;
    __syncthreads();
    if (tid == 0)
        part[NBLK_COLLECT + bid] =
            make_float4(0.f, 0.f, 0.f, s_w1[0] + s_w1[1] + s_w1[2] + s_w1[3]);
}

// Sum the 1664 per-block partials (double accumulation) and emit the 5 outputs.
__global__ __launch_bounds__(512) void k_reduce(
        const float4* __restrict__ part, float* __restrict__ out) {
    int t = threadIdx.x;
    double x = 0.0, w = 0.0, p = 0.0, c = 0.0;
    for (int i = t; i < NPART; i += 512) {
        float4 v = part[i];
        x += (double)v.x; w += (double)v.y; p += (double)v.z; c += (double)v.w;
    }
    for (int off = 32; off; off >>= 1) {
        x += __shfl_down(x, off);
        w += __shfl_down(w, off);
        p += __shfl_down(p, off);
        c += __shfl_down(c, off);
    }
    __shared__ double sx[8], sw[8], sp[8], sc[8];
    int wid = t >> 6, lane = t & 63;
    if (lane == 0) { sx[wid] = x; sw[wid] = w; sp[wid] = p; sc[wid] = c; }
    __syncthreads();
    if (t == 0) {
        double X = 0, W = 0, P = 0, C = 0;
        for (int i = 0; i < 8; ++i) { X += sx[i]; W += sw[i]; P += sp[i]; C += sc[i]; }
        double xy = 5.0 * X / 32.0;
        double wh = 5.0 * W / 32.0;
        double cf = C / 32.0;
        double pb = P / 32.0;
        out[0] = (float)(xy + wh + cf + pb);
        out[1] = (float)xy;
        out[2] = (float)wh;
        out[3] = (float)cf;
        out[4] = (float)pb;
    }
}

extern "C" void kernel_launch(void* const* d_in, const int* in_sizes, int n_in,
                              void* d_out, int out_size, void* d_ws, size_t ws_size,
                              hipStream_t stream) {
    const float* fm0  = (const float*)d_in[0];
    const float* yt0  = (const float*)d_in[1];
    const float* fm1  = (const float*)d_in[2];
    const float* yt1  = (const float*)d_in[3];
    const float* fm2  = (const float*)d_in[4];
    const float* yt2  = (const float*)d_in[5];
    const float* anch = (const float*)d_in[6];
    float* out = (float*)d_out;

    char* ws = (char*)d_ws;
    int*    cnt  = (int*)(ws + OFF_CNT);
    float4* part = (float4*)(ws + OFF_PART);
    float*  tgt  = (float*)(ws + OFF_TGT);
    int*    tgtn = (int*)(ws + OFF_TGTN);

    k_collect<<<NBLK_COLLECT, 512, 0, stream>>>(
        fm0, fm1, fm2, yt0, yt1, yt2, anch, cnt, tgt, tgtn, part);
    k_conf<<<NBLK_CONF, 256, 0, stream>>>(
        fm0, fm1, fm2, anch, cnt, tgt, tgtn, part);
    k_reduce<<<1, 512, 0, stream>>>(part, out);
}